// Round 8
// baseline (309.207 us; speedup 1.0000x reference)
//
#include <hip/hip_runtime.h>

#define BB 8
#define LLEN 896
#define DMODEL 320
#define NHEAD 10
#define DHEAD 32
#define DINNER 1280
#define ROWS (BB*LLEN)   // 7168

typedef float f32x4 __attribute__((ext_vector_type(4)));
typedef float f32x16 __attribute__((ext_vector_type(16)));
typedef __bf16 bf16x8 __attribute__((ext_vector_type(8)));

__device__ __forceinline__ float bf2f(unsigned short u) {
    union { unsigned int i; float f; } x;
    x.i = ((unsigned int)u) << 16;
    return x.f;
}
__device__ __forceinline__ unsigned short f2bf(float f) {
    unsigned int u = __float_as_uint(f);
    u += 0x7FFF + ((u >> 16) & 1);   // round-to-nearest-even
    return (unsigned short)(u >> 16);
}

#define GLOAD16(g, l)                                                              \
    __builtin_amdgcn_global_load_lds(                                              \
        (const __attribute__((address_space(1))) void*)(g),                        \
        (__attribute__((address_space(3))) void*)(__attribute__((address_space(3))) char*)(l), \
        16, 0, 0)

// ---------------- weight transpose fp32 -> bf16 (dst[C][R] = src[R][C]) ----------------
__global__ __launch_bounds__(256) void transpose_bf16(const float* __restrict__ src,
                                                      unsigned short* __restrict__ dst,
                                                      int R, int C) {
    __shared__ float tile[32][33];
    int c0 = blockIdx.x * 32;
    int r0 = blockIdx.y * 32;
    int tx = threadIdx.x & 31, ty = threadIdx.x >> 5;
#pragma unroll
    for (int k = 0; k < 4; ++k) {
        int yy = ty + 8 * k;
        tile[yy][tx] = src[(size_t)(r0 + yy) * C + c0 + tx];
    }
    __syncthreads();
#pragma unroll
    for (int k = 0; k < 4; ++k) {
        int yy = ty + 8 * k;
        dst[(size_t)(c0 + yy) * R + r0 + tx] = f2bf(tile[tx][yy]);
    }
}

// ---------------- mask/bias pre-pass, m-tiled layout ----------------
// combo[((b*28 + mt)*896 + n)*32 + ml] = bf16(-g*D[b,n,m]+nm[b,n,m]) | bf16(mask[b,n,m])<<16
__global__ __launch_bounds__(256) void prepass(const float* __restrict__ D,
                                               const float* __restrict__ nm,
                                               const float* __restrict__ mk,
                                               const float* __restrict__ gamma,
                                               unsigned int* __restrict__ combo) {
    __shared__ unsigned int tile[32][33];   // [n_local][m_local]
    int mt = blockIdx.x, m0 = mt * 32;
    int n0 = blockIdx.y * 32;
    int b = blockIdx.z;
    int sn = (n0 < 128) ? 0 : (n0 < 384) ? 1 : 2;   // tiles never straddle 128/384
    int sm = (m0 < 128) ? 0 : (m0 < 384) ? 1 : 2;
    float g = gamma[sn * 4 + sm];
    int tx = threadIdx.x & 31, ty = threadIdx.x >> 5;
#pragma unroll
    for (int k = 0; k < 4; ++k) {
        int nl = ty + 8 * k;
        size_t idx = ((size_t)b * LLEN + n0 + nl) * LLEN + m0 + tx;
        float bias = -g * D[idx] + nm[idx];
        tile[nl][tx] = (unsigned int)f2bf(bias) | ((unsigned int)f2bf(mk[idx]) << 16);
    }
    __syncthreads();
#pragma unroll
    for (int k = 0; k < 4; ++k) {
        int nl = ty + 8 * k;
        combo[(((size_t)b * 28 + mt) * LLEN + n0 + nl) * 32 + tx] = tile[nl][tx];
    }
}

// ---------------- V transpose: Vt[b][h][d][m] from qkv ----------------
__global__ __launch_bounds__(256) void vt_kernel(const unsigned short* __restrict__ qkv,
                                                 unsigned short* __restrict__ Vt) {
    __shared__ unsigned short tile[32][33];   // [m_local][d]
    int mt = blockIdx.x, h = blockIdx.y, b = blockIdx.z;
    int tx = threadIdx.x & 31, ty = threadIdx.x >> 5;
#pragma unroll
    for (int k = 0; k < 4; ++k) {
        int ml = ty + 8 * k;
        tile[ml][tx] = qkv[((size_t)(b * LLEN) + mt * 32 + ml) * 960 + h * 96 + tx];
    }
    __syncthreads();
#pragma unroll
    for (int k = 0; k < 4; ++k) {
        int d = ty + 8 * k;
        Vt[(((size_t)b * NHEAD + h) * 32 + d) * LLEN + mt * 32 + tx] = tile[tx][d];
    }
}

// ---------------- LayerNorm (fp32 in, bf16 out) ----------------
__global__ __launch_bounds__(320) void ln_kernel(const float* __restrict__ x,
                                                 const float* __restrict__ g,
                                                 const float* __restrict__ bia,
                                                 unsigned short* __restrict__ y) {
    int row = blockIdx.x;
    int t = threadIdx.x;
    float v = x[(size_t)row * DMODEL + t];
    float s = v;
#pragma unroll
    for (int o = 1; o < 64; o <<= 1) s += __shfl_xor(s, o, 64);
    __shared__ float red[10];
    int w = t >> 6;
    if ((t & 63) == 0) red[w] = s;
    __syncthreads();
    float mu = (red[0] + red[1] + red[2] + red[3] + red[4]) * (1.0f / DMODEL);
    float d = v - mu;
    float s2 = d * d;
#pragma unroll
    for (int o = 1; o < 64; o <<= 1) s2 += __shfl_xor(s2, o, 64);
    if ((t & 63) == 0) red[5 + w] = s2;
    __syncthreads();
    float var = (red[5] + red[6] + red[7] + red[8] + red[9]) * (1.0f / DMODEL);
    float inv = rsqrtf(var + 1e-5f);
    y[(size_t)row * DMODEL + t] = f2bf(d * inv * g[t] + bia[t]);
}

// ---------------- bf16 MFMA GEMM: 128x64 tile, BK=64, double-buffered 2-phase ----------
// global_load_lds staging of tile t+1 overlaps MFMA on tile t; counted vmcnt(6), raw
// s_barrier (never drain to 0 mid-loop). XOR swizzle per rule #21: linear LDS dest,
// inverse-swizzled GLOBAL source chunk (tid&7)^(srow&7), swizzled read slot g^(row&7).
// EPI: 0 = +bias -> bf16 ; 1 = +resid(f32) -> f32 ; 2 = +bias,relu -> bf16 ; 3 = +bias+resid -> f32
template <int EPI>
__global__ __launch_bounds__(256) void gemm_bt(const unsigned short* __restrict__ A,
                                               const unsigned short* __restrict__ BT,
                                               const float* __restrict__ bias,
                                               const float* __restrict__ resid,
                                               void* __restrict__ outv,
                                               int M, int N, int K) {
    __shared__ unsigned short As[2][128][64];   // 2 x 16 KB
    __shared__ unsigned short Bs[2][64][64];    // 2 x 8 KB
    int tid = threadIdx.x;
    int m0 = blockIdx.x * 128;
    int n0 = blockIdx.y * 64;
    int wid = tid >> 6, l = tid & 63;
    int wr = wid >> 1, wc = wid & 1;
    int lr = l & 15, lh = l >> 4;
    int srow = tid >> 3;                    // 0..31 within a 32-row stage chunk
    int sslot = (tid & 7) ^ (srow & 7);     // inverse-swizzled source chunk

    f32x4 acc[4][2];
#pragma unroll
    for (int mi = 0; mi < 4; ++mi)
#pragma unroll
        for (int ni = 0; ni < 2; ++ni) acc[mi][ni] = (f32x4){0.f, 0.f, 0.f, 0.f};

#define STAGE(buf, k0)                                                              \
    {                                                                               \
        _Pragma("unroll")                                                           \
        for (int i = 0; i < 4; ++i)                                                 \
            GLOAD16(&A[(size_t)(m0 + i * 32 + srow) * K + (k0) + sslot * 8],        \
                    (char*)&As[buf][0][0] + i * 4096 + tid * 16);                   \
        _Pragma("unroll")                                                           \
        for (int i = 0; i < 2; ++i)                                                 \
            GLOAD16(&BT[(size_t)(n0 + i * 32 + srow) * K + (k0) + sslot * 8],       \
                    (char*)&Bs[buf][0][0] + i * 4096 + tid * 16);                   \
    }

    int nsteps = K >> 6;
    STAGE(0, 0);
    int cur = 0;
#pragma unroll 1
    for (int t = 0; t < nsteps; ++t) {
        if (t + 1 < nsteps) {
            STAGE(cur ^ 1, (t + 1) * 64);
            asm volatile("s_waitcnt vmcnt(6)" ::: "memory");   // tile-t loads done
        } else {
            asm volatile("s_waitcnt vmcnt(0)" ::: "memory");
        }
        __builtin_amdgcn_s_barrier();
#pragma unroll
        for (int kk = 0; kk < 2; ++kk) {
            int gch = kk * 4 + lh;          // global k-chunk this frag needs
            int sl = gch ^ (lr & 7);        // swizzled LDS slot (row&7 == lr&7)
            bf16x8 b0 = *(const bf16x8*)&Bs[cur][wc * 32 + lr][sl * 8];
            bf16x8 b1 = *(const bf16x8*)&Bs[cur][wc * 32 + 16 + lr][sl * 8];
#pragma unroll
            for (int mi = 0; mi < 4; ++mi) {
                bf16x8 a = *(const bf16x8*)&As[cur][wr * 64 + mi * 16 + lr][sl * 8];
                acc[mi][0] = __builtin_amdgcn_mfma_f32_16x16x32_bf16(a, b0, acc[mi][0], 0, 0, 0);
                acc[mi][1] = __builtin_amdgcn_mfma_f32_16x16x32_bf16(a, b1, acc[mi][1], 0, 0, 0);
            }
        }
        __builtin_amdgcn_s_barrier();
        cur ^= 1;
    }
#undef STAGE

    unsigned short* outb = (unsigned short*)outv;
    float* outf = (float*)outv;
#pragma unroll
    for (int mi = 0; mi < 4; ++mi)
#pragma unroll
        for (int ni = 0; ni < 2; ++ni) {
            int col = n0 + wc * 32 + ni * 16 + lr;
            float bv = (EPI != 1) ? bias[col] : 0.f;
#pragma unroll
            for (int j = 0; j < 4; ++j) {
                int row = m0 + wr * 64 + mi * 16 + lh * 4 + j;
                float v = acc[mi][ni][j];
                if (EPI == 0 || EPI == 2 || EPI == 3) v += bv;
                if (EPI == 2) v = fmaxf(v, 0.0f);
                if (EPI == 1 || EPI == 3) v += resid[(size_t)row * N + col];
                if (EPI == 0 || EPI == 2) outb[(size_t)row * N + col] = f2bf(v);
                else outf[(size_t)row * N + col] = v;
            }
        }
}

// ---------------- MFMA attention: 1 wave/block, 2240 blocks, dual m-chains ----------
// R7 post-mortem: Occupancy 11.5% (~1 wave/SIMD) => latency-bound with no TLP.
// Fix: grid (b*28, h) = 2240 single-wave blocks (~9 waves/CU resident) + two
// independent m-chains per wave (tiles 0-13 / 14-27; partials add, no online max).
__global__ __launch_bounds__(64) void attn_mfma(const unsigned short* __restrict__ qkv,
                                                const unsigned short* __restrict__ Vt,
                                                const unsigned int* __restrict__ combo,
                                                unsigned short* __restrict__ attn) {
    int l = threadIdx.x;
    int c = l & 31;
    int hi = l >> 5;
    int nt = blockIdx.x % 28;
    int b = blockIdx.x / 28;
    int h = blockIdx.y;
    int n0 = nt * 32;

    size_t qbase = ((size_t)(b * LLEN + n0 + c)) * 960 + h * 96 + 32 + hi * 8;
    bf16x8 qB0 = *(const bf16x8*)&qkv[qbase];
    bf16x8 qB1 = *(const bf16x8*)&qkv[qbase + 16];

    const unsigned int* cbase = combo + ((size_t)b * 28 * LLEN + n0 + c) * 32;   // + mt*896*32
    size_t kbase = (size_t)b * LLEN * 960 + h * 96 + 64 + hi * 8;                // + m*960
    const unsigned short* vrow = Vt + (((size_t)b * NHEAD + h) * 32 + c) * LLEN; // + m

#define ALOAD(mt, K0, K1, V1_, V2_, X4)                                     \
    {                                                                       \
        size_t krow = kbase + (size_t)((mt) * 32 + c) * 960;                \
        K0 = *(const bf16x8*)&qkv[krow];                                    \
        K1 = *(const bf16x8*)&qkv[krow + 16];                               \
        V1_ = *(const bf16x8*)&vrow[(mt) * 32 + hi * 8];                    \
        V2_ = *(const bf16x8*)&vrow[(mt) * 32 + 16 + hi * 8];               \
        const unsigned int* cp = cbase + (size_t)(mt) * (LLEN * 32);        \
        X4[0] = *(const int4*)&cp[4 * hi];                                  \
        X4[1] = *(const int4*)&cp[8 + 4 * hi];                              \
        X4[2] = *(const int4*)&cp[16 + 4 * hi];                             \
        X4[3] = *(const int4*)&cp[24 + 4 * hi];                             \
    }

#define ACOMPUTE(K0, K1, V1_, V2_, X4, OACC, LSUM)                                    \
    {                                                                                 \
        f32x16 sacc = {0.f,0.f,0.f,0.f,0.f,0.f,0.f,0.f,0.f,0.f,0.f,0.f,0.f,0.f,0.f,0.f}; \
        sacc = __builtin_amdgcn_mfma_f32_32x32x16_bf16(K0, qB0, sacc, 0, 0, 0);       \
        sacc = __builtin_amdgcn_mfma_f32_32x32x16_bf16(K1, qB1, sacc, 0, 0, 0);       \
        float p[16];                                                                  \
        _Pragma("unroll")                                                             \
        for (int r = 0; r < 16; ++r) {                                                \
            unsigned int cm = ((const unsigned int*)X4)[r];                           \
            float bias = __uint_as_float(cm << 16);                                   \
            float mk = __uint_as_float(cm & 0xffff0000u);                             \
            float s = fmaf(sacc[r], 0.17677669529663687f, bias);                      \
            float e = __expf(s);                                                      \
            LSUM += e;                                                                \
            p[r] = e * mk;                                                            \
        }                                                                             \
        unsigned int u[8], x[8];                                                      \
        _Pragma("unroll")                                                             \
        for (int j = 0; j < 8; ++j) {                                                 \
            union { __bf16 h2[2]; unsigned int w; } pk;                               \
            pk.h2[0] = (__bf16)p[2 * j];                                              \
            pk.h2[1] = (__bf16)p[2 * j + 1];                                          \
            u[j] = pk.w;                                                              \
            x[j] = (unsigned int)__shfl_xor((int)u[j], 32, 64);                       \
        }                                                                             \
        union { unsigned int w[4]; bf16x8 v; } a1, a2;                                \
        if (hi == 0) {                                                                \
            a1.w[0] = u[0]; a1.w[1] = u[1]; a1.w[2] = x[0]; a1.w[3] = x[1];           \
            a2.w[0] = u[4]; a2.w[1] = u[5]; a2.w[2] = x[4]; a2.w[3] = x[5];           \
        } else {                                                                      \
            a1.w[0] = x[2]; a1.w[1] = x[3]; a1.w[2] = u[2]; a1.w[3] = u[3];           \
            a2.w[0] = x[6]; a2.w[1] = x[7]; a2.w[2] = u[6]; a2.w[3] = u[7];           \
        }                                                                             \
        OACC = __builtin_amdgcn_mfma_f32_32x32x16_bf16(a1.v, V1_, OACC, 0, 0, 0);     \
        OACC = __builtin_amdgcn_mfma_f32_32x32x16_bf16(a2.v, V2_, OACC, 0, 0, 0);     \
    }

    f32x16 oaccA = {0.f,0.f,0.f,0.f,0.f,0.f,0.f,0.f,0.f,0.f,0.f,0.f,0.f,0.f,0.f,0.f};
    f32x16 oaccB = oaccA;
    float lsumA = 0.f, lsumB = 0.f;
    bf16x8 k0A, k1A, v1A, v2A; int4 xA[4];
    bf16x8 k0B, k1B, v1B, v2B; int4 xB[4];
    ALOAD(0, k0A, k1A, v1A, v2A, xA);
    ALOAD(14, k0B, k1B, v1B, v2B, xB);
#pragma unroll 1
    for (int i = 0; i < 14; ++i) {
        ACOMPUTE(k0A, k1A, v1A, v2A, xA, oaccA, lsumA);
        if (i < 13) ALOAD(i + 1, k0A, k1A, v1A, v2A, xA);
        ACOMPUTE(k0B, k1B, v1B, v2B, xB, oaccB, lsumB);
        if (i < 13) ALOAD(i + 15, k0B, k1B, v1B, v2B, xB);
    }
#undef ALOAD
#undef ACOMPUTE

    f32x16 oacc = oaccA + oaccB;
    float lsum = lsumA + lsumB;
    lsum += __shfl_xor(lsum, 32, 64);
    float invs = 1.0f / lsum;     // lane c holds inv for column n=c
#pragma unroll
    for (int r = 0; r < 16; ++r) {
        int n = (r & 3) + 8 * (r >> 2) + 4 * hi;
        float o = oacc[r] * __shfl(invs, n, 64);
        o = (o >= 0.f) ? o : 0.01f * o;   // leaky_relu(0.01)
        attn[((size_t)(b * LLEN + n0 + n)) * DMODEL + h * DHEAD + c] = f2bf(o);
    }
}

// ---------------- launch ----------------
extern "C" void kernel_launch(void* const* d_in, const int* in_sizes, int n_in,
                              void* d_out, int out_size, void* d_ws, size_t ws_size,
                              hipStream_t stream) {
    const float* Z     = (const float*)d_in[0];
    const float* Dm    = (const float*)d_in[1];
    const float* nmask = (const float*)d_in[2];
    const float* mask  = (const float*)d_in[3];
    const float* gamma = (const float*)d_in[4];
    const float* w_qkv = (const float*)d_in[5];
    const float* b_qkv = (const float*)d_in[6];
    const float* w_o   = (const float*)d_in[7];
    const float* ln1g  = (const float*)d_in[8];
    const float* ln1b  = (const float*)d_in[9];
    const float* ln2g  = (const float*)d_in[10];
    const float* ln2b  = (const float*)d_in[11];
    const float* w1    = (const float*)d_in[12];
    const float* b1    = (const float*)d_in[13];
    const float* w2    = (const float*)d_in[14];
    const float* b2    = (const float*)d_in[15];

    char* ws = (char*)d_ws;
    unsigned short* Zn    = (unsigned short*)(ws + 0);         // 7168x320 bf16
    unsigned short* qkv   = (unsigned short*)(ws + 4587520);   // 7168x960 bf16
    unsigned short* attn  = (unsigned short*)(ws + 18350080);  // 7168x320 bf16
    float*          Zres  = (float*)(ws + 22937600);           // 7168x320 f32
    unsigned short* Zn2   = (unsigned short*)(ws + 32112640);  // 7168x320 bf16
    unsigned short* Hbuf  = (unsigned short*)(ws + 36700160);  // 7168x1280 bf16
    unsigned short* wqkvT = (unsigned short*)(ws + 55050240);  // 960x320 bf16
    unsigned short* woT   = (unsigned short*)(ws + 55664640);  // 320x320 bf16
    unsigned short* w1T   = (unsigned short*)(ws + 55869440);  // 1280x320 bf16
    unsigned short* w2T   = (unsigned short*)(ws + 56688640);  // 320x1280 bf16
    unsigned int*   combo = (unsigned int*)(ws + 57507840);    // 8x28x896x32 u32 (25.7MB)
    unsigned short* Vtb   = (unsigned short*)(ws + 83197952);  // 8x10x32x896 bf16 (4.6MB)

    // weight prep
    transpose_bf16<<<dim3(960 / 32, 320 / 32), 256, 0, stream>>>(w_qkv, wqkvT, 320, 960);
    transpose_bf16<<<dim3(320 / 32, 320 / 32), 256, 0, stream>>>(w_o, woT, 320, 320);
    transpose_bf16<<<dim3(1280 / 32, 320 / 32), 256, 0, stream>>>(w1, w1T, 320, 1280);
    transpose_bf16<<<dim3(320 / 32, 1280 / 32), 256, 0, stream>>>(w2, w2T, 1280, 320);

    // mask/bias pre-pass (head-independent, read once)
    prepass<<<dim3(28, 28, 8), 256, 0, stream>>>(Dm, nmask, mask, gamma, combo);

    // LN1
    ln_kernel<<<ROWS, 320, 0, stream>>>(Z, ln1g, ln1b, Zn);

    // QKV GEMM: Zn(7168x320) @ w_qkv(320x960) + b_qkv -> qkv bf16
    gemm_bt<0><<<dim3(ROWS / 128, 960 / 64), 256, 0, stream>>>(Zn, wqkvT, b_qkv, nullptr,
                                                               (void*)qkv, ROWS, 960, 320);

    // V transpose for PV B-fragments
    vt_kernel<<<dim3(28, NHEAD, BB), 256, 0, stream>>>(qkv, Vtb);

    // MFMA attention -> leaky_relu -> attn bf16
    attn_mfma<<<dim3(BB * 28, NHEAD), 64, 0, stream>>>(qkv, Vtb, combo, attn);

    // W_O GEMM + residual Z -> Zres f32
    gemm_bt<1><<<dim3(ROWS / 128, 320 / 64), 256, 0, stream>>>(attn, woT, nullptr, Z,
                                                               (void*)Zres, ROWS, 320, 320);

    // LN2
    ln_kernel<<<ROWS, 320, 0, stream>>>(Zres, ln2g, ln2b, Zn2);

    // FFN1: Zn2 @ w1 + b1, relu -> H bf16
    gemm_bt<2><<<dim3(ROWS / 128, 1280 / 64), 256, 0, stream>>>(Zn2, w1T, b1, nullptr,
                                                                (void*)Hbuf, ROWS, 1280, 320);

    // FFN2: H @ w2 + b2 + Zres -> out f32
    gemm_bt<3><<<dim3(ROWS / 128, 320 / 64), 256, 0, stream>>>(Hbuf, w2T, b2, Zres,
                                                               d_out, ROWS, 320, 1280);
}

// Round 9
// 298.167 us; speedup vs baseline: 1.0370x; 1.0370x over previous
//
#include <hip/hip_runtime.h>

#define BB 8
#define LLEN 896
#define DMODEL 320
#define NHEAD 10
#define DHEAD 32
#define DINNER 1280
#define ROWS (BB*LLEN)   // 7168

typedef float f32x4 __attribute__((ext_vector_type(4)));
typedef float f32x16 __attribute__((ext_vector_type(16)));
typedef __bf16 bf16x8 __attribute__((ext_vector_type(8)));

__device__ __forceinline__ float bf2f(unsigned short u) {
    union { unsigned int i; float f; } x;
    x.i = ((unsigned int)u) << 16;
    return x.f;
}
__device__ __forceinline__ unsigned short f2bf(float f) {
    unsigned int u = __float_as_uint(f);
    u += 0x7FFF + ((u >> 16) & 1);   // round-to-nearest-even
    return (unsigned short)(u >> 16);
}

#define GLOAD16(g, l)                                                              \
    __builtin_amdgcn_global_load_lds(                                              \
        (const __attribute__((address_space(1))) void*)(g),                        \
        (__attribute__((address_space(3))) void*)(__attribute__((address_space(3))) char*)(l), \
        16, 0, 0)

// ---------------- fused weight transpose fp32 -> bf16 (4 weights, 1 dispatch) ----------
// regions (blockIdx.x): [0,300) w_qkv 320x960 ; [300,400) w_o 320x320 ;
//                       [400,800) w1 320x1280 ; [800,1200) w2 1280x320
__global__ __launch_bounds__(256) void prep_all(const float* __restrict__ w_qkv,
                                                const float* __restrict__ w_o,
                                                const float* __restrict__ w1,
                                                const float* __restrict__ w2,
                                                unsigned short* __restrict__ wqkvT,
                                                unsigned short* __restrict__ woT,
                                                unsigned short* __restrict__ w1T,
                                                unsigned short* __restrict__ w2T) {
    __shared__ float tile[32][33];
    int bid = blockIdx.x;
    const float* src; unsigned short* dst; int R, C, t;
    if (bid < 300)      { src = w_qkv; dst = wqkvT; R = 320;  C = 960;  t = bid; }
    else if (bid < 400) { src = w_o;   dst = woT;   R = 320;  C = 320;  t = bid - 300; }
    else if (bid < 800) { src = w1;    dst = w1T;   R = 320;  C = 1280; t = bid - 400; }
    else                { src = w2;    dst = w2T;   R = 1280; C = 320;  t = bid - 800; }
    int tiles_x = C >> 5;
    int c0 = (t % tiles_x) * 32;
    int r0 = (t / tiles_x) * 32;
    int tx = threadIdx.x & 31, ty = threadIdx.x >> 5;
#pragma unroll
    for (int k = 0; k < 4; ++k) {
        int yy = ty + 8 * k;
        tile[yy][tx] = src[(size_t)(r0 + yy) * C + c0 + tx];
    }
    __syncthreads();
#pragma unroll
    for (int k = 0; k < 4; ++k) {
        int yy = ty + 8 * k;
        dst[(size_t)(c0 + yy) * R + r0 + tx] = f2bf(tile[tx][yy]);
    }
}

// ---------------- mask/bias pre-pass, m-tiled layout, bias pre-scaled by log2(e) -------
// combo[((b*28 + mt)*896 + n)*32 + ml] = bf16((-g*D+nm)*log2e) | bf16(mask)<<16
__global__ __launch_bounds__(256) void prepass(const float* __restrict__ D,
                                               const float* __restrict__ nm,
                                               const float* __restrict__ mk,
                                               const float* __restrict__ gamma,
                                               unsigned int* __restrict__ combo) {
    __shared__ unsigned int tile[32][33];   // [n_local][m_local]
    int mt = blockIdx.x, m0 = mt * 32;
    int n0 = blockIdx.y * 32;
    int b = blockIdx.z;
    int sn = (n0 < 128) ? 0 : (n0 < 384) ? 1 : 2;   // tiles never straddle 128/384
    int sm = (m0 < 128) ? 0 : (m0 < 384) ? 1 : 2;
    float g = gamma[sn * 4 + sm];
    int tx = threadIdx.x & 31, ty = threadIdx.x >> 5;
#pragma unroll
    for (int k = 0; k < 4; ++k) {
        int nl = ty + 8 * k;
        size_t idx = ((size_t)b * LLEN + n0 + nl) * LLEN + m0 + tx;
        float bias = (-g * D[idx] + nm[idx]) * 1.4426950408889634f;   // log2(e)
        tile[nl][tx] = (unsigned int)f2bf(bias) | ((unsigned int)f2bf(mk[idx]) << 16);
    }
    __syncthreads();
#pragma unroll
    for (int k = 0; k < 4; ++k) {
        int nl = ty + 8 * k;
        combo[(((size_t)b * 28 + mt) * LLEN + n0 + nl) * 32 + tx] = tile[nl][tx];
    }
}

// ---------------- LayerNorm (fp32 in, bf16 out) ----------------
__global__ __launch_bounds__(320) void ln_kernel(const float* __restrict__ x,
                                                 const float* __restrict__ g,
                                                 const float* __restrict__ bia,
                                                 unsigned short* __restrict__ y) {
    int row = blockIdx.x;
    int t = threadIdx.x;
    float v = x[(size_t)row * DMODEL + t];
    float s = v;
#pragma unroll
    for (int o = 1; o < 64; o <<= 1) s += __shfl_xor(s, o, 64);
    __shared__ float red[10];
    int w = t >> 6;
    if ((t & 63) == 0) red[w] = s;
    __syncthreads();
    float mu = (red[0] + red[1] + red[2] + red[3] + red[4]) * (1.0f / DMODEL);
    float d = v - mu;
    float s2 = d * d;
#pragma unroll
    for (int o = 1; o < 64; o <<= 1) s2 += __shfl_xor(s2, o, 64);
    if ((t & 63) == 0) red[5 + w] = s2;
    __syncthreads();
    float var = (red[5] + red[6] + red[7] + red[8] + red[9]) * (1.0f / DMODEL);
    float inv = rsqrtf(var + 1e-5f);
    y[(size_t)row * DMODEL + t] = f2bf(d * inv * g[t] + bia[t]);
}

// ---------------- bf16 MFMA GEMM: 128x64 tile, BK=64, double-buffered 2-phase ----------
// XOR swizzle per rule #21 (linear LDS dest / inverse-swizzled global src / swizzled read).
// EPI 0: +bias -> bf16 (and if vtout: scatter V-columns into Vt[b][h][d][m])
// EPI 1: +resid(f32) -> f32 ; EPI 2: +bias,relu -> bf16 ; EPI 3: +bias+resid -> f32
template <int EPI>
__global__ __launch_bounds__(256) void gemm_bt(const unsigned short* __restrict__ A,
                                               const unsigned short* __restrict__ BT,
                                               const float* __restrict__ bias,
                                               const float* __restrict__ resid,
                                               void* __restrict__ outv,
                                               unsigned short* __restrict__ vtout,
                                               int M, int N, int K) {
    __shared__ unsigned short As[2][128][64];   // 2 x 16 KB
    __shared__ unsigned short Bs[2][64][64];    // 2 x 8 KB
    int tid = threadIdx.x;
    int m0 = blockIdx.x * 128;
    int n0 = blockIdx.y * 64;
    int wid = tid >> 6, l = tid & 63;
    int wr = wid >> 1, wc = wid & 1;
    int lr = l & 15, lh = l >> 4;
    int srow = tid >> 3;                    // 0..31 within a 32-row stage chunk
    int sslot = (tid & 7) ^ (srow & 7);     // inverse-swizzled source chunk

    f32x4 acc[4][2];
#pragma unroll
    for (int mi = 0; mi < 4; ++mi)
#pragma unroll
        for (int ni = 0; ni < 2; ++ni) acc[mi][ni] = (f32x4){0.f, 0.f, 0.f, 0.f};

#define STAGE(buf, k0)                                                              \
    {                                                                               \
        _Pragma("unroll")                                                           \
        for (int i = 0; i < 4; ++i)                                                 \
            GLOAD16(&A[(size_t)(m0 + i * 32 + srow) * K + (k0) + sslot * 8],        \
                    (char*)&As[buf][0][0] + i * 4096 + tid * 16);                   \
        _Pragma("unroll")                                                           \
        for (int i = 0; i < 2; ++i)                                                 \
            GLOAD16(&BT[(size_t)(n0 + i * 32 + srow) * K + (k0) + sslot * 8],       \
                    (char*)&Bs[buf][0][0] + i * 4096 + tid * 16);                   \
    }

    int nsteps = K >> 6;
    STAGE(0, 0);
    int cur = 0;
#pragma unroll 1
    for (int t = 0; t < nsteps; ++t) {
        if (t + 1 < nsteps) {
            STAGE(cur ^ 1, (t + 1) * 64);
            asm volatile("s_waitcnt vmcnt(6)" ::: "memory");   // tile-t loads done
        } else {
            asm volatile("s_waitcnt vmcnt(0)" ::: "memory");
        }
        __builtin_amdgcn_s_barrier();
#pragma unroll
        for (int kk = 0; kk < 2; ++kk) {
            int gch = kk * 4 + lh;          // global k-chunk this frag needs
            int sl = gch ^ (lr & 7);        // swizzled LDS slot (row&7 == lr&7)
            bf16x8 b0 = *(const bf16x8*)&Bs[cur][wc * 32 + lr][sl * 8];
            bf16x8 b1 = *(const bf16x8*)&Bs[cur][wc * 32 + 16 + lr][sl * 8];
#pragma unroll
            for (int mi = 0; mi < 4; ++mi) {
                bf16x8 a = *(const bf16x8*)&As[cur][wr * 64 + mi * 16 + lr][sl * 8];
                acc[mi][0] = __builtin_amdgcn_mfma_f32_16x16x32_bf16(a, b0, acc[mi][0], 0, 0, 0);
                acc[mi][1] = __builtin_amdgcn_mfma_f32_16x16x32_bf16(a, b1, acc[mi][1], 0, 0, 0);
            }
        }
        __builtin_amdgcn_s_barrier();
        cur ^= 1;
    }
#undef STAGE

    unsigned short* outb = (unsigned short*)outv;
    float* outf = (float*)outv;
#pragma unroll
    for (int mi = 0; mi < 4; ++mi)
#pragma unroll
        for (int ni = 0; ni < 2; ++ni) {
            int col = n0 + wc * 32 + ni * 16 + lr;
            float bv = (EPI != 1) ? bias[col] : 0.f;
            unsigned short vv[4];
#pragma unroll
            for (int j = 0; j < 4; ++j) {
                int row = m0 + wr * 64 + mi * 16 + lh * 4 + j;
                float v = acc[mi][ni][j];
                if (EPI == 0 || EPI == 2 || EPI == 3) v += bv;
                if (EPI == 2) v = fmaxf(v, 0.0f);
                if (EPI == 1 || EPI == 3) v += resid[(size_t)row * N + col];
                if (EPI == 0 || EPI == 2) {
                    unsigned short ob = f2bf(v);
                    outb[(size_t)row * N + col] = ob;
                    vv[j] = ob;
                } else outf[(size_t)row * N + col] = v;
            }
            if (EPI == 0 && vtout) {
                // V region: qkv col layout per head = [V:0..31 | Q | K] at h*96
                int cf = n0 + wc * 32 + ni * 16;   // fragment base col (uniform)
                int h = cf / 96;
                int d0 = cf - h * 96;              // 0,16,32,48,64,80
                if (d0 < 32) {
                    int b2 = blockIdx.x / 7;       // 896 = 7*128: block within one b
                    int mf = (blockIdx.x % 7) * 128 + wr * 64 + mi * 16 + lh * 4;
                    unsigned short* vp =
                        vtout + (((size_t)b2 * NHEAD + h) * 32 + d0 + lr) * LLEN + mf;
                    *(ushort4*)vp = *(ushort4*)vv;  // m, m+1, m+2, m+3
                }
            }
        }
}

// ---------------- MFMA attention ----------------
// Grid (2, 224): x = head-half (adjacent blocks share combo), y = b*28+nt.
// 320 threads = 5 waves, wave = head. Dual independent m-chains (0-13 / 14-27) for ILP.
// VALU diet: exp2 (bias pre-scaled by log2e in prepass) + v_cvt_pk_bf16_f32 pack.
__global__ __launch_bounds__(320) void attn_mfma(const unsigned short* __restrict__ qkv,
                                                 const unsigned short* __restrict__ Vt,
                                                 const unsigned int* __restrict__ combo,
                                                 unsigned short* __restrict__ attn) {
    int tid = threadIdx.x;
    int h = blockIdx.x * 5 + (tid >> 6);
    int l = tid & 63;
    int c = l & 31;
    int hi = l >> 5;
    int nt = blockIdx.y % 28;
    int b = blockIdx.y / 28;
    int n0 = nt * 32;

    size_t qbase = ((size_t)(b * LLEN + n0 + c)) * 960 + h * 96 + 32 + hi * 8;
    bf16x8 qB0 = *(const bf16x8*)&qkv[qbase];
    bf16x8 qB1 = *(const bf16x8*)&qkv[qbase + 16];

    const unsigned int* cbase = combo + ((size_t)b * 28 * LLEN + n0 + c) * 32;   // + mt*896*32
    size_t kbase = (size_t)b * LLEN * 960 + h * 96 + 64 + hi * 8;                // + m*960
    const unsigned short* vrow = Vt + (((size_t)b * NHEAD + h) * 32 + c) * LLEN; // + m

#define ALOAD(mt, K0, K1, V1_, V2_, X4)                                     \
    {                                                                       \
        size_t krow = kbase + (size_t)((mt) * 32 + c) * 960;                \
        K0 = *(const bf16x8*)&qkv[krow];                                    \
        K1 = *(const bf16x8*)&qkv[krow + 16];                               \
        V1_ = *(const bf16x8*)&vrow[(mt) * 32 + hi * 8];                    \
        V2_ = *(const bf16x8*)&vrow[(mt) * 32 + 16 + hi * 8];               \
        const unsigned int* cp = cbase + (size_t)(mt) * (LLEN * 32);        \
        X4[0] = *(const int4*)&cp[4 * hi];                                  \
        X4[1] = *(const int4*)&cp[8 + 4 * hi];                              \
        X4[2] = *(const int4*)&cp[16 + 4 * hi];                             \
        X4[3] = *(const int4*)&cp[24 + 4 * hi];                             \
    }

// s' = sacc * (1/sqrt(32))*log2e + bias'  ;  e = 2^s'
#define ACOMPUTE(K0, K1, V1_, V2_, X4, OACC, LSUM)                                    \
    {                                                                                 \
        f32x16 sacc = {0.f,0.f,0.f,0.f,0.f,0.f,0.f,0.f,0.f,0.f,0.f,0.f,0.f,0.f,0.f,0.f}; \
        sacc = __builtin_amdgcn_mfma_f32_32x32x16_bf16(K0, qB0, sacc, 0, 0, 0);       \
        sacc = __builtin_amdgcn_mfma_f32_32x32x16_bf16(K1, qB1, sacc, 0, 0, 0);       \
        float p[16];                                                                  \
        _Pragma("unroll")                                                             \
        for (int r = 0; r < 16; ++r) {                                                \
            unsigned int cm = ((const unsigned int*)X4)[r];                           \
            float bias = __uint_as_float(cm << 16);                                   \
            float mk = __uint_as_float(cm & 0xffff0000u);                             \
            float e = exp2f(fmaf(sacc[r], 0.25500527f, bias));                        \
            LSUM += e;                                                                \
            p[r] = e * mk;                                                            \
        }                                                                             \
        unsigned int u[8], x[8];                                                      \
        _Pragma("unroll")                                                             \
        for (int j = 0; j < 8; ++j) {                                                 \
            asm("v_cvt_pk_bf16_f32 %0, %1, %2"                                        \
                : "=v"(u[j]) : "v"(p[2 * j]), "v"(p[2 * j + 1]));                     \
            x[j] = (unsigned int)__shfl_xor((int)u[j], 32, 64);                       \
        }                                                                             \
        union { unsigned int w[4]; bf16x8 v; } a1, a2;                                \
        if (hi == 0) {                                                                \
            a1.w[0] = u[0]; a1.w[1] = u[1]; a1.w[2] = x[0]; a1.w[3] = x[1];           \
            a2.w[0] = u[4]; a2.w[1] = u[5]; a2.w[2] = x[4]; a2.w[3] = x[5];           \
        } else {                                                                      \
            a1.w[0] = x[2]; a1.w[1] = x[3]; a1.w[2] = u[2]; a1.w[3] = u[3];           \
            a2.w[0] = x[6]; a2.w[1] = x[7]; a2.w[2] = u[6]; a2.w[3] = u[7];           \
        }                                                                             \
        OACC = __builtin_amdgcn_mfma_f32_32x32x16_bf16(a1.v, V1_, OACC, 0, 0, 0);     \
        OACC = __builtin_amdgcn_mfma_f32_32x32x16_bf16(a2.v, V2_, OACC, 0, 0, 0);     \
    }

    f32x16 oaccA = {0.f,0.f,0.f,0.f,0.f,0.f,0.f,0.f,0.f,0.f,0.f,0.f,0.f,0.f,0.f,0.f};
    f32x16 oaccB = oaccA;
    float lsumA = 0.f, lsumB = 0.f;
    bf16x8 k0A, k1A, v1A, v2A; int4 xA[4];
    bf16x8 k0B, k1B, v1B, v2B; int4 xB[4];
    ALOAD(0, k0A, k1A, v1A, v2A, xA);
    ALOAD(14, k0B, k1B, v1B, v2B, xB);
#pragma unroll 1
    for (int i = 0; i < 14; ++i) {
        ACOMPUTE(k0A, k1A, v1A, v2A, xA, oaccA, lsumA);
        if (i < 13) ALOAD(i + 1, k0A, k1A, v1A, v2A, xA);
        ACOMPUTE(k0B, k1B, v1B, v2B, xB, oaccB, lsumB);
        if (i < 13) ALOAD(i + 15, k0B, k1B, v1B, v2B, xB);
    }
#undef ALOAD
#undef ACOMPUTE

    f32x16 oacc = oaccA + oaccB;
    float lsum = lsumA + lsumB;
    lsum += __shfl_xor(lsum, 32, 64);
    float invs = 1.0f / lsum;     // lane c holds inv for column n=c
#pragma unroll
    for (int r = 0; r < 16; ++r) {
        int n = (r & 3) + 8 * (r >> 2) + 4 * hi;
        float o = oacc[r] * __shfl(invs, n, 64);
        o = (o >= 0.f) ? o : 0.01f * o;   // leaky_relu(0.01)
        attn[((size_t)(b * LLEN + n0 + n)) * DMODEL + h * DHEAD + c] = f2bf(o);
    }
}

// ---------------- launch ----------------
extern "C" void kernel_launch(void* const* d_in, const int* in_sizes, int n_in,
                              void* d_out, int out_size, void* d_ws, size_t ws_size,
                              hipStream_t stream) {
    const float* Z     = (const float*)d_in[0];
    const float* Dm    = (const float*)d_in[1];
    const float* nmask = (const float*)d_in[2];
    const float* mask  = (const float*)d_in[3];
    const float* gamma = (const float*)d_in[4];
    const float* w_qkv = (const float*)d_in[5];
    const float* b_qkv = (const float*)d_in[6];
    const float* w_o   = (const float*)d_in[7];
    const float* ln1g  = (const float*)d_in[8];
    const float* ln1b  = (const float*)d_in[9];
    const float* ln2g  = (const float*)d_in[10];
    const float* ln2b  = (const float*)d_in[11];
    const float* w1    = (const float*)d_in[12];
    const float* b1    = (const float*)d_in[13];
    const float* w2    = (const float*)d_in[14];
    const float* b2    = (const float*)d_in[15];

    char* ws = (char*)d_ws;
    unsigned short* Zn    = (unsigned short*)(ws + 0);         // 7168x320 bf16
    unsigned short* qkv   = (unsigned short*)(ws + 4587520);   // 7168x960 bf16
    unsigned short* attn  = (unsigned short*)(ws + 18350080);  // 7168x320 bf16
    float*          Zres  = (float*)(ws + 22937600);           // 7168x320 f32
    unsigned short* Zn2   = (unsigned short*)(ws + 32112640);  // 7168x320 bf16
    unsigned short* Hbuf  = (unsigned short*)(ws + 36700160);  // 7168x1280 bf16
    unsigned short* wqkvT = (unsigned short*)(ws + 55050240);  // 960x320 bf16
    unsigned short* woT   = (unsigned short*)(ws + 55664640);  // 320x320 bf16
    unsigned short* w1T   = (unsigned short*)(ws + 55869440);  // 1280x320 bf16
    unsigned short* w2T   = (unsigned short*)(ws + 56688640);  // 320x1280 bf16
    unsigned int*   combo = (unsigned int*)(ws + 57507840);    // 8x28x896x32 u32 (25.7MB)
    unsigned short* Vtb   = (unsigned short*)(ws + 83197952);  // 8x10x32x896 bf16 (4.6MB)

    // weight prep: 4 transposes, one dispatch
    prep_all<<<1200, 256, 0, stream>>>(w_qkv, w_o, w1, w2, wqkvT, woT, w1T, w2T);

    // mask/bias pre-pass (head-independent, read once; bias pre-scaled by log2e)
    prepass<<<dim3(28, 28, 8), 256, 0, stream>>>(Dm, nmask, mask, gamma, combo);

    // LN1
    ln_kernel<<<ROWS, 320, 0, stream>>>(Z, ln1g, ln1b, Zn);

    // QKV GEMM (+ fused Vt scatter): Zn(7168x320) @ w_qkv(320x960) + b_qkv -> qkv bf16
    gemm_bt<0><<<dim3(ROWS / 128, 960 / 64), 256, 0, stream>>>(Zn, wqkvT, b_qkv, nullptr,
                                                               (void*)qkv, Vtb, ROWS, 960, 320);

    // MFMA attention -> leaky_relu -> attn bf16
    attn_mfma<<<dim3(2, BB * 28), 320, 0, stream>>>(qkv, Vtb, combo, attn);

    // W_O GEMM + residual Z -> Zres f32
    gemm_bt<1><<<dim3(ROWS / 128, 320 / 64), 256, 0, stream>>>(attn, woT, nullptr, Z,
                                                               (void*)Zres, nullptr, ROWS, 320, 320);

    // LN2
    ln_kernel<<<ROWS, 320, 0, stream>>>(Zres, ln2g, ln2b, Zn2);

    // FFN1: Zn2 @ w1 + b1, relu -> H bf16
    gemm_bt<2><<<dim3(ROWS / 128, 1280 / 64), 256, 0, stream>>>(Zn2, w1T, b1, nullptr,
                                                                (void*)Hbuf, nullptr, ROWS, 1280, 320);

    // FFN2: H @ w2 + b2 + Zres -> out f32
    gemm_bt<3><<<dim3(ROWS / 128, 320 / 64), 256, 0, stream>>>(Hbuf, w2T, b2, Zres,
                                                               d_out, nullptr, ROWS, 320, 1280);
}